// Round 7
// baseline (143.043 us; speedup 1.0000x reference)
//
#include <hip/hip_runtime.h>
#include <math.h>

#define KC 33            // clusters
#define ED 32            // embedding dim
#define KE (KC * ED)     // 1056
#define PAD 33           // padded leading dim for LDS tiles

// accum geometry
#define BPB_A 64         // blocks per batch
#define TPA 128          // points per staged tile
#define NSLOT 8          // half-waves per 256-thread block
// hinge geometry (barrier-free 8-lanes-per-point form)
#define BPB_H 256        // blocks per batch -> 2048 blocks, 8 blocks/CU
#define CPH 256          // points per hinge block
#define NIT 8            // iterations (32 points per block-iter)

// ws layout (floats): sums[B*KE] | counts[B*KC] | var[B]

__global__ void k_zero(float* __restrict__ ws, int n, float* __restrict__ out) {
    int i = blockIdx.x * blockDim.x + threadIdx.x;
    if (i < n) ws[i] = 0.f;
    if (i == 0) out[0] = 0.f;
}

// Pass 1: per-(b,k) embedding sums + fused label histogram. UNCHANGED from the
// measured-131.0 round-6 kernel (isolated A/B: only k_hinge changes this round).
__global__ __launch_bounds__(256) void k_accum(const float* __restrict__ emb,
                                               const int* __restrict__ lab,
                                               float* __restrict__ sums,
                                               float* __restrict__ counts, int N) {
    __shared__ float s_tile[TPA * PAD];      // 16.9 KB
    __shared__ float s_priv[NSLOT * KE];     // 33 KB
    __shared__ int   s_lab[TPA];
    __shared__ float s_hist[2 * KC];
    int t = threadIdx.x;
    for (int i = t; i < NSLOT * KE; i += 256) s_priv[i] = 0.f;
    if (t < 2 * KC) s_hist[t] = 0.f;

    int b     = blockIdx.x / BPB_A;
    int blk   = blockIdx.x % BPB_A;
    int chunk = N / BPB_A;                   // 1024
    int e     = t & 31;
    int slot  = t >> 5;
    size_t pbase = (size_t)b * N + (size_t)blk * chunk;
    const int NT = chunk / TPA;              // 8 tiles

    // prefetch tile 0
    const float4* g4 = (const float4*)(emb + pbase * ED);
    float4 r0 = g4[t], r1 = g4[t + 256], r2 = g4[t + 512], r3 = g4[t + 768];
    int rl = 0;
    if (t < TPA) rl = lab[pbase + t];
    __syncthreads();                          // priv + hist init done

    for (int tb = 0; tb < NT; tb++) {
        // unpack staged registers into padded tile
        {
            int f, p, m;
            f = t;        p = f >> 3; m = (f & 7) * 4;
            { float* d = &s_tile[PAD * p + m]; d[0]=r0.x; d[1]=r0.y; d[2]=r0.z; d[3]=r0.w; }
            f = t + 256;  p = f >> 3; m = (f & 7) * 4;
            { float* d = &s_tile[PAD * p + m]; d[0]=r1.x; d[1]=r1.y; d[2]=r1.z; d[3]=r1.w; }
            f = t + 512;  p = f >> 3; m = (f & 7) * 4;
            { float* d = &s_tile[PAD * p + m]; d[0]=r2.x; d[1]=r2.y; d[2]=r2.z; d[3]=r2.w; }
            f = t + 768;  p = f >> 3; m = (f & 7) * 4;
            { float* d = &s_tile[PAD * p + m]; d[0]=r3.x; d[1]=r3.y; d[2]=r3.z; d[3]=r3.w; }
        }
        if (t < TPA) {
            s_lab[t] = rl;
            atomicAdd(&s_hist[(t >> 6) * KC + rl], 1.f);   // fused histogram
        }
        __syncthreads();

        // prefetch next tile while computing this one
        if (tb + 1 < NT) {
            const float4* gn = (const float4*)(emb + (pbase + (size_t)(tb + 1) * TPA) * ED);
            r0 = gn[t]; r1 = gn[t + 256]; r2 = gn[t + 512]; r3 = gn[t + 768];
            if (t < TPA) rl = lab[pbase + (size_t)(tb + 1) * TPA + t];
        }

        float* priv = &s_priv[slot * KE];
#pragma unroll
        for (int st = 0; st < TPA / NSLOT; st++) {
            int pt = st * NSLOT + slot;
            float x = s_tile[pt * PAD + e];
            int   k = s_lab[pt];
            priv[k * ED + e] += x;           // private: no atomic; bank=e: free
        }
        __syncthreads();
    }

    for (int i = t; i < KE; i += 256) {
        float v = 0.f;
#pragma unroll
        for (int s = 0; s < NSLOT; s++) v += s_priv[s * KE + i];
        atomicAdd(&sums[(size_t)b * KE + i], v);
    }
    if (t < KC)
        atomicAdd(&counts[b * KC + t], s_hist[t] + s_hist[KC + t]);
}

// Pass 2: barrier-free hinge. 8 lanes co-own one point (lane = 4 dims via
// float4), so global loads are perfectly coalesced (1KB/wave-instr) with NO
// LDS data tile and NO per-tile barriers -- the old form coupled 4 waves
// through 2 barriers/tile at 4 blocks/CU and measured latency-bound (VALU 4.6%,
// occ 26%, HBM 9%). Here: 2048 blocks, ~6KB LDS, 32 waves/CU, waves fully
// independent after one setup barrier; d2 reduced with 3 shfl_xor steps.
// Center reads use padded [KC][33] so bank = (k+4q+j)%32 spreads across k.
__global__ __launch_bounds__(256) void k_hinge(const float* __restrict__ emb,
                                               const int* __restrict__ lab,
                                               const float* __restrict__ sums,
                                               const float* __restrict__ counts,
                                               float* __restrict__ var, int N) {
    __shared__ float s_ctr[KC * PAD];        // 4.3 KB, padded
    __shared__ float s_cnt[KC];
    __shared__ float s_inv[KC];
    __shared__ int   s_lab[CPH];
    __shared__ float s_red[4];
    int t     = threadIdx.x;
    int b     = blockIdx.x / BPB_H;
    int blk   = blockIdx.x % BPB_H;
    size_t pbase = (size_t)b * N + (size_t)blk * CPH;
    const float4* g4 = (const float4*)(emb + pbase * ED);

    // issue data loads before the setup chain (latency hides under it)
    float4 xcur = g4[t];                     // iter 0: points 0..31
    s_lab[t] = lab[pbase + t];               // all 256 labels, coalesced

    if (t < KC) {
        float c = counts[b * KC + t];
        s_cnt[t] = fmaxf(c, 1.f);
        s_inv[t] = (t > 0 && c > 0.f) ? 1.f / fmaxf(c, 1.f) : 0.f;
    }
    __syncthreads();
    for (int i = t; i < KE; i += 256) {
        int k = i >> 5, e = i & 31;
        s_ctr[k * PAD + e] = sums[(size_t)b * KE + i] / s_cnt[k];
    }
    __syncthreads();                         // the only barrier before reduce

    int q = t & 7;                           // dim-quad within point
    float hs = 0.f;
#pragma unroll
    for (int i = 0; i < NIT; i++) {
        float4 xnext;
        if (i + 1 < NIT) xnext = g4[(i + 1) * 256 + t];   // prefetch
        int p_local = ((i << 8) + t) >> 3;   // 0..255
        int k = s_lab[p_local];
        const float* cr = &s_ctr[k * PAD + q * 4];
        float d2 = 0.f, d;
        d = xcur.x - cr[0]; d2 = fmaf(d, d, d2);
        d = xcur.y - cr[1]; d2 = fmaf(d, d, d2);
        d = xcur.z - cr[2]; d2 = fmaf(d, d, d2);
        d = xcur.w - cr[3]; d2 = fmaf(d, d, d2);
        d2 += __shfl_xor(d2, 1);
        d2 += __shfl_xor(d2, 2);
        d2 += __shfl_xor(d2, 4);             // all 8 lanes hold full ||x-c||^2
        float dist = sqrtf(fmaxf(d2, 1e-12f));
        float hv = fmaxf(dist - 0.5f, 0.f) * s_inv[k];
        hs += (q == 0) ? hv : 0.f;
        xcur = xnext;
    }

    // block reduction of hs (one value per point-owner lane, 0 elsewhere)
    hs += __shfl_xor(hs, 1);  hs += __shfl_xor(hs, 2);  hs += __shfl_xor(hs, 4);
    hs += __shfl_xor(hs, 8);  hs += __shfl_xor(hs, 16); hs += __shfl_xor(hs, 32);
    if ((t & 63) == 0) s_red[t >> 6] = hs;
    __syncthreads();
    if (t == 0)
        atomicAdd(&var[b], s_red[0] + s_red[1] + s_red[2] + s_red[3]);
}

// Epilogue: one block per batch; recompute centers from sums/counts.
__global__ __launch_bounds__(256) void k_final(const float* __restrict__ sums,
                                               const float* __restrict__ counts,
                                               const float* __restrict__ var,
                                               float* __restrict__ out, int B) {
    __shared__ float s_ctr[KE];
    __shared__ float s_cnt[KC];
    __shared__ float s_reg[KC];
    __shared__ int   s_prs[KC];
    __shared__ float s_red[256];
    int b = blockIdx.x;
    int t = threadIdx.x;

    if (t < KC) {
        float c = counts[b * KC + t];
        s_cnt[t] = fmaxf(c, 1.f);
        s_prs[t] = (t > 0 && c > 0.f) ? 1 : 0;
    }
    __syncthreads();
    for (int i = t; i < KE; i += 256)
        s_ctr[i] = sums[(size_t)b * KE + i] / s_cnt[i >> 5];
    __syncthreads();
    if (t < KC) {
        float n2 = 0.f;
        for (int e2 = 0; e2 < ED; e2++) { float c = s_ctr[t * ED + e2]; n2 += c * c; }
        s_reg[t] = s_prs[t] ? sqrtf(fmaxf(n2, 1e-12f)) : 0.f;
    }
    __syncthreads();

    float psum = 0.f;
    for (int q = t; q < KC * KC; q += 256) {
        int i = q / KC, j = q % KC;
        if (i < j && s_prs[i] && s_prs[j]) {
            float d2 = 0.f;
            for (int e2 = 0; e2 < ED; e2++) {
                float d = s_ctr[i * ED + e2] - s_ctr[j * ED + e2];
                d2 += d * d;
            }
            float cd = sqrtf(fmaxf(d2, 1e-12f));
            psum += fmaxf(3.0f - cd, 0.f);   // 2*DELTA_D = 3.0
        }
    }
    s_red[t] = psum;
    __syncthreads();
    for (int s = 128; s > 0; s >>= 1) {
        if (t < s) s_red[t] += s_red[t + s];
        __syncthreads();
    }

    if (t == 0) {
        float reg = 0.f; int n = 0;
        for (int k = 0; k < KC; k++) { reg += s_reg[k]; n += s_prs[k]; }
        float nf = (float)n;
        float variance_term = var[b] / fmaxf(nf, 1.f);
        float npairs = nf * (nf - 1.f) * 0.5f;
        float distance_term = s_red[0] / fmaxf(npairs, 1.f);
        float reg_term = reg / fmaxf(nf, 1.f);
        float pb = variance_term + distance_term + 0.001f * reg_term;
        if (n == 0) pb = 0.f;
        atomicAdd(out, pb / (float)B);
    }
}

extern "C" void kernel_launch(void* const* d_in, const int* in_sizes, int n_in,
                              void* d_out, int out_size, void* d_ws, size_t ws_size,
                              hipStream_t stream) {
    const float* emb = (const float*)d_in[0];
    const int*   lab = (const int*)d_in[1];
    float* out = (float*)d_out;

    const int B = 8;
    const int N = in_sizes[1] / B;   // 65536

    float* sums   = (float*)d_ws;
    float* counts = sums + (size_t)B * KE;
    float* var    = counts + (size_t)B * KC;

    int zn = B * KE + B * KC + B;
    k_zero<<<(zn + 255) / 256, 256, 0, stream>>>(sums, zn, out);
    k_accum<<<B * BPB_A, 256, 0, stream>>>(emb, lab, sums, counts, N);
    k_hinge<<<B * BPB_H, 256, 0, stream>>>(emb, lab, sums, counts, var, N);
    k_final<<<B, 256, 0, stream>>>(sums, counts, var, out, B);
}

// Round 8
// 127.295 us; speedup vs baseline: 1.1237x; 1.1237x over previous
//
#include <hip/hip_runtime.h>
#include <math.h>

#define KC 33            // clusters
#define ED 32            // embedding dim
#define KE (KC * ED)     // 1056
#define PAD 33           // padded leading dim for LDS tiles

// accum geometry: 1024 blocks, 512 points/block, barrier-free half-wave strips
#define BPB_A 128
// hinge geometry: 1024 blocks, 512 points/block, wave-private 64-row strips
#define BPB_H 128

// ws layout (floats): sums[B*KE] | counts[B*KC] | var[B]

__global__ void k_zero(float* __restrict__ ws, int n, float* __restrict__ out) {
    int i = blockIdx.x * blockDim.x + threadIdx.x;
    if (i < n) ws[i] = 0.f;
    if (i == 0) out[0] = 0.f;
}

// Pass 1: per-(b,k) sums + histogram. Data movement = r6 (float4 staging,
// padded LDS, bank-free per-half-wave private copies) but the staging tile is
// HALF-WAVE-PRIVATE (4 rows each), so the 16-group main loop has ZERO barriers
// (within-wave LDS ordering is program-order + lgkmcnt, compiler-inserted).
// r6's form ran 2 barriers/tile x 8 tiles coupling 4 waves at pipeline depth 1
// -> latency-bound at ~1.6 TB/s effective. 4 blocks/CU (39KB LDS).
__global__ __launch_bounds__(256) void k_accum(const float* __restrict__ emb,
                                               const int* __restrict__ lab,
                                               float* __restrict__ sums,
                                               float* __restrict__ counts, int N) {
    __shared__ float s_stage[8 * 4 * PAD];       // 4.2 KB: 8 half-wave strips
    __shared__ float s_priv[8 * KE];             // 33.8 KB private sum copies
    __shared__ unsigned short s_lab[512];
    __shared__ float s_hist[2 * KC];
    int t = threadIdx.x;
    int b     = blockIdx.x / BPB_A;
    int blk   = blockIdx.x % BPB_A;
    int chunk = N / BPB_A;                       // 512
    int e  = t & 31;                             // dim lane
    int s  = t >> 5;                             // half-wave slot 0..7
    int w  = t >> 6;                             // wave 0..3
    int h  = (t >> 5) & 1;                       // half within wave
    int l5 = t & 31;
    size_t pbase = (size_t)b * N + (size_t)blk * chunk;
    const float4* g4 = (const float4*)(emb + pbase * ED);

    for (int i = t; i < 8 * KE; i += 256) s_priv[i] = 0.f;
    if (t < 2 * KC) s_hist[t] = 0.f;

    // stage labels once (int2 per thread, coalesced) + histogram once
    int2 lp = ((const int2*)(lab + pbase))[t];
    s_lab[2 * t]     = (unsigned short)lp.x;
    s_lab[2 * t + 1] = (unsigned short)lp.y;
    __syncthreads();                             // the only barrier before flush
    {
        float* hh = &s_hist[(t >> 7) * KC];
        atomicAdd(&hh[lp.x], 1.f);
        atomicAdd(&hh[lp.y], 1.f);
    }

    // wave w owns points [w*128, w*128+128); per group g: 8 points, halves 4+4.
    float* strip = &s_stage[s * 4 * PAD];
    float* priv  = &s_priv[s * KE];
    int fbase = w * 1024 + h * 32 + l5;          // float4 idx: + g*64
    float4 cur = g4[fbase];
    for (int g = 0; g < 16; g++) {
        {   // stage this half-wave's 4 points (512B contiguous was loaded)
            float* d = &strip[(l5 >> 3) * PAD + (l5 & 7) * 4];
            d[0] = cur.x; d[1] = cur.y; d[2] = cur.z; d[3] = cur.w;
        }
        if (g + 1 < 16) cur = g4[fbase + (g + 1) * 64];   // depth-1 prefetch
        int lbase = w * 128 + g * 8 + h * 4;
#pragma unroll
        for (int j = 0; j < 4; j++) {
            float x = strip[j * PAD + e];        // bank (4s+j+e)%32: free
            int   k = (int)s_lab[lbase + j];     // broadcast within half-wave
            priv[k * ED + e] += x;               // private; bank=e: free
        }
    }
    __syncthreads();

    for (int i = t; i < KE; i += 256) {
        float v = 0.f;
#pragma unroll
        for (int c = 0; c < 8; c++) v += s_priv[c * KE + i];
        atomicAdd(&sums[(size_t)b * KE + i], v);
    }
    if (t < KC)
        atomicAdd(&counts[b * KC + t], s_hist[t] + s_hist[KC + t]);
}

// Pass 2: lane-owns-point hinge, r6 body with the 256-row tile split into 4
// WAVE-PRIVATE 64-row strips -> no barriers in the group loop; depth-1
// register prefetch of the next 64-point group. 4 blocks/CU (~39KB LDS).
__global__ __launch_bounds__(256) void k_hinge(const float* __restrict__ emb,
                                               const int* __restrict__ lab,
                                               const float* __restrict__ sums,
                                               const float* __restrict__ counts,
                                               float* __restrict__ var, int N) {
    __shared__ float s_wtile[4 * 64 * PAD];      // 33.8 KB: 4 wave strips
    __shared__ float s_ctr[KC * PAD];            // 4.3 KB padded centers
    __shared__ float s_cnt[KC];
    __shared__ float s_inv[KC];
    __shared__ unsigned short s_lab[512];
    __shared__ float s_red[4];
    int t = threadIdx.x;
    int b     = blockIdx.x / BPB_H;
    int blk   = blockIdx.x % BPB_H;
    int chunk = N / BPB_H;                       // 512
    int w = t >> 6, l = t & 63;
    size_t pbase = (size_t)b * N + (size_t)blk * chunk;
    const float4* g4 = (const float4*)(emb + pbase * ED);

    // stage labels (int2 per thread, coalesced)
    int2 lp = ((const int2*)(lab + pbase))[t];
    s_lab[2 * t]     = (unsigned short)lp.x;
    s_lab[2 * t + 1] = (unsigned short)lp.y;

    if (t < KC) {
        float c = counts[b * KC + t];
        s_cnt[t] = fmaxf(c, 1.f);
        s_inv[t] = (t > 0 && c > 0.f) ? 1.f / fmaxf(c, 1.f) : 0.f;
    }
    __syncthreads();
    for (int i = t; i < KE; i += 256) {
        int k = i >> 5, e = i & 31;
        s_ctr[k * PAD + e] = sums[(size_t)b * KE + i] / s_cnt[k];
    }
    __syncthreads();                             // ctr+labels ready (only barriers)

    // wave w owns points [w*128, w*128+128): 2 groups of 64 (1 point/lane)
    float* strip = &s_wtile[w * 64 * PAD];
    int fb = w * 1024 + l;                       // float4 idx: + g*512 + i*64
    float4 r0 = g4[fb],       r1 = g4[fb + 64],  r2 = g4[fb + 128], r3 = g4[fb + 192];
    float4 r4 = g4[fb + 256], r5 = g4[fb + 320], r6 = g4[fb + 384], r7 = g4[fb + 448];

    float hs = 0.f;
    for (int g = 0; g < 2; g++) {
        {   // unpack 8 regs into wave strip (r6 pattern, wave-scoped)
            int f, p, m;
            f = l;        p = f >> 3; m = (f & 7) * 4;
            { float* d = &strip[PAD * p + m]; d[0]=r0.x; d[1]=r0.y; d[2]=r0.z; d[3]=r0.w; }
            f = l + 64;   p = f >> 3; m = (f & 7) * 4;
            { float* d = &strip[PAD * p + m]; d[0]=r1.x; d[1]=r1.y; d[2]=r1.z; d[3]=r1.w; }
            f = l + 128;  p = f >> 3; m = (f & 7) * 4;
            { float* d = &strip[PAD * p + m]; d[0]=r2.x; d[1]=r2.y; d[2]=r2.z; d[3]=r2.w; }
            f = l + 192;  p = f >> 3; m = (f & 7) * 4;
            { float* d = &strip[PAD * p + m]; d[0]=r3.x; d[1]=r3.y; d[2]=r3.z; d[3]=r3.w; }
            f = l + 256;  p = f >> 3; m = (f & 7) * 4;
            { float* d = &strip[PAD * p + m]; d[0]=r4.x; d[1]=r4.y; d[2]=r4.z; d[3]=r4.w; }
            f = l + 320;  p = f >> 3; m = (f & 7) * 4;
            { float* d = &strip[PAD * p + m]; d[0]=r5.x; d[1]=r5.y; d[2]=r5.z; d[3]=r5.w; }
            f = l + 384;  p = f >> 3; m = (f & 7) * 4;
            { float* d = &strip[PAD * p + m]; d[0]=r6.x; d[1]=r6.y; d[2]=r6.z; d[3]=r6.w; }
            f = l + 448;  p = f >> 3; m = (f & 7) * 4;
            { float* d = &strip[PAD * p + m]; d[0]=r7.x; d[1]=r7.y; d[2]=r7.z; d[3]=r7.w; }
        }
        if (g + 1 < 2) {                         // depth-1 prefetch next group
            int nb = fb + 512;
            r0 = g4[nb];       r1 = g4[nb + 64];  r2 = g4[nb + 128]; r3 = g4[nb + 192];
            r4 = g4[nb + 256]; r5 = g4[nb + 320]; r6 = g4[nb + 384]; r7 = g4[nb + 448];
        }

        int   k  = (int)s_lab[w * 128 + g * 64 + l];
        float iv = s_inv[k];
        const float* xr = &strip[l * PAD];       // bank (l+j)%32: 2-way free
        const float* cr = &s_ctr[k * PAD];
        float d2 = 0.f;
#pragma unroll
        for (int j = 0; j < ED; j++) {
            float d = xr[j] - cr[j];
            d2 = fmaf(d, d, d2);
        }
        float dist = sqrtf(fmaxf(d2, 1e-12f));
        hs += fmaxf(dist - 0.5f, 0.f) * iv;
    }

    // block reduction of hs
    hs += __shfl_xor(hs, 1);  hs += __shfl_xor(hs, 2);  hs += __shfl_xor(hs, 4);
    hs += __shfl_xor(hs, 8);  hs += __shfl_xor(hs, 16); hs += __shfl_xor(hs, 32);
    if ((t & 63) == 0) s_red[t >> 6] = hs;
    __syncthreads();
    if (t == 0)
        atomicAdd(&var[b], s_red[0] + s_red[1] + s_red[2] + s_red[3]);
}

// Epilogue: one block per batch; recompute centers from sums/counts.
__global__ __launch_bounds__(256) void k_final(const float* __restrict__ sums,
                                               const float* __restrict__ counts,
                                               const float* __restrict__ var,
                                               float* __restrict__ out, int B) {
    __shared__ float s_ctr[KE];
    __shared__ float s_cnt[KC];
    __shared__ float s_reg[KC];
    __shared__ int   s_prs[KC];
    __shared__ float s_red[256];
    int b = blockIdx.x;
    int t = threadIdx.x;

    if (t < KC) {
        float c = counts[b * KC + t];
        s_cnt[t] = fmaxf(c, 1.f);
        s_prs[t] = (t > 0 && c > 0.f) ? 1 : 0;
    }
    __syncthreads();
    for (int i = t; i < KE; i += 256)
        s_ctr[i] = sums[(size_t)b * KE + i] / s_cnt[i >> 5];
    __syncthreads();
    if (t < KC) {
        float n2 = 0.f;
        for (int e2 = 0; e2 < ED; e2++) { float c = s_ctr[t * ED + e2]; n2 += c * c; }
        s_reg[t] = s_prs[t] ? sqrtf(fmaxf(n2, 1e-12f)) : 0.f;
    }
    __syncthreads();

    float psum = 0.f;
    for (int q = t; q < KC * KC; q += 256) {
        int i = q / KC, j = q % KC;
        if (i < j && s_prs[i] && s_prs[j]) {
            float d2 = 0.f;
            for (int e2 = 0; e2 < ED; e2++) {
                float d = s_ctr[i * ED + e2] - s_ctr[j * ED + e2];
                d2 += d * d;
            }
            float cd = sqrtf(fmaxf(d2, 1e-12f));
            psum += fmaxf(3.0f - cd, 0.f);   // 2*DELTA_D = 3.0
        }
    }
    s_red[t] = psum;
    __syncthreads();
    for (int s = 128; s > 0; s >>= 1) {
        if (t < s) s_red[t] += s_red[t + s];
        __syncthreads();
    }

    if (t == 0) {
        float reg = 0.f; int n = 0;
        for (int k = 0; k < KC; k++) { reg += s_reg[k]; n += s_prs[k]; }
        float nf = (float)n;
        float variance_term = var[b] / fmaxf(nf, 1.f);
        float npairs = nf * (nf - 1.f) * 0.5f;
        float distance_term = s_red[0] / fmaxf(npairs, 1.f);
        float reg_term = reg / fmaxf(nf, 1.f);
        float pb = variance_term + distance_term + 0.001f * reg_term;
        if (n == 0) pb = 0.f;
        atomicAdd(out, pb / (float)B);
    }
}

extern "C" void kernel_launch(void* const* d_in, const int* in_sizes, int n_in,
                              void* d_out, int out_size, void* d_ws, size_t ws_size,
                              hipStream_t stream) {
    const float* emb = (const float*)d_in[0];
    const int*   lab = (const int*)d_in[1];
    float* out = (float*)d_out;

    const int B = 8;
    const int N = in_sizes[1] / B;   // 65536

    float* sums   = (float*)d_ws;
    float* counts = sums + (size_t)B * KE;
    float* var    = counts + (size_t)B * KC;

    int zn = B * KE + B * KC + B;
    k_zero<<<(zn + 255) / 256, 256, 0, stream>>>(sums, zn, out);
    k_accum<<<B * BPB_A, 256, 0, stream>>>(emb, lab, sums, counts, N);
    k_hinge<<<B * BPB_H, 256, 0, stream>>>(emb, lab, sums, counts, var, N);
    k_final<<<B, 256, 0, stream>>>(sums, counts, var, out, B);
}